// Round 1
// baseline (487.217 us; speedup 1.0000x reference)
//
#include <hip/hip_runtime.h>
#include <math.h>

#define DDIM 2048      // hidden dim
#define NEXP 64        // experts
#define NSEL 8         // top-k
#define TM   64        // tokens per block
#define KC   64        // k-chunk
#define NCH  (DDIM / KC)
#define LDX  68        // padded LDS row stride (floats): 68*4=272B, 16B-aligned, breaks 256B bank aliasing
#define LSTR 65        // epilogue logits/probs row stride (conflict-free scalar scans)

__global__ __launch_bounds__(256, 1)
void router_kernel(const float* __restrict__ x,
                   const float* __restrict__ w,
                   float* __restrict__ out,
                   int tokens)
{
    __shared__ float xs[2][TM][LDX];
    __shared__ float ws[2][NEXP][LDX];
    __shared__ float tkp[TM][NSEL];
    __shared__ int   tki[TM][NSEL];

    const int tid = threadIdx.x;
    const int tx  = tid & 15;    // expert lane: e = tx + 16*j
    const int ty  = tid >> 4;    // token lane:  t = ty + 16*i
    const int tok0 = blockIdx.x * TM;

    float acc[4][4] = {};

    // ---- stage chunk 0 into buffer 0 (reg-staged so rows can be padded) ----
    {
        #pragma unroll
        for (int it = 0; it < 4; ++it) {
            const int f   = tid + 256 * it;      // float4 id 0..1023
            const int row = f >> 4;              // 0..63
            const int c4  = f & 15;              // 0..15
            float4 vx = *reinterpret_cast<const float4*>(&x[(tok0 + row) * DDIM + c4 * 4]);
            float4 vw = *reinterpret_cast<const float4*>(&w[row * DDIM + c4 * 4]);
            *reinterpret_cast<float4*>(&xs[0][row][c4 * 4]) = vx;
            *reinterpret_cast<float4*>(&ws[0][row][c4 * 4]) = vw;
        }
    }

    // ---- main K loop: compute chunk c from buf (c&1), prefetch c+1 into regs,
    //      ds_write into buf ((c+1)&1). One barrier per chunk. ----
    for (int c = 0; c < NCH; ++c) {
        __syncthreads();

        float4 rx[4], rw[4];
        const bool pf = (c + 1 < NCH);
        if (pf) {
            const int k0 = (c + 1) * KC;
            #pragma unroll
            for (int it = 0; it < 4; ++it) {
                const int f   = tid + 256 * it;
                const int row = f >> 4;
                const int c4  = f & 15;
                rx[it] = *reinterpret_cast<const float4*>(&x[(tok0 + row) * DDIM + k0 + c4 * 4]);
                rw[it] = *reinterpret_cast<const float4*>(&w[row * DDIM + k0 + c4 * 4]);
            }
        }

        const int buf = c & 1;
        float accc[4][4] = {};   // per-chunk accumulator (accuracy: 2-level summation)
        #pragma unroll
        for (int kq = 0; kq < 16; ++kq) {
            float4 xv[4], wv[4];
            #pragma unroll
            for (int i = 0; i < 4; ++i)
                xv[i] = *reinterpret_cast<const float4*>(&xs[buf][ty + 16 * i][kq * 4]);
            #pragma unroll
            for (int j = 0; j < 4; ++j)
                wv[j] = *reinterpret_cast<const float4*>(&ws[buf][tx + 16 * j][kq * 4]);
            #pragma unroll
            for (int i = 0; i < 4; ++i) {
                #pragma unroll
                for (int j = 0; j < 4; ++j) {
                    accc[i][j] = fmaf(xv[i].x, wv[j].x, accc[i][j]);
                    accc[i][j] = fmaf(xv[i].y, wv[j].y, accc[i][j]);
                    accc[i][j] = fmaf(xv[i].z, wv[j].z, accc[i][j]);
                    accc[i][j] = fmaf(xv[i].w, wv[j].w, accc[i][j]);
                }
            }
        }
        #pragma unroll
        for (int i = 0; i < 4; ++i)
            #pragma unroll
            for (int j = 0; j < 4; ++j)
                acc[i][j] += accc[i][j];

        if (pf) {
            const int nbuf = buf ^ 1;
            #pragma unroll
            for (int it = 0; it < 4; ++it) {
                const int f   = tid + 256 * it;
                const int row = f >> 4;
                const int c4  = f & 15;
                *reinterpret_cast<float4*>(&xs[nbuf][row][c4 * 4]) = rx[it];
                *reinterpret_cast<float4*>(&ws[nbuf][row][c4 * 4]) = rw[it];
            }
        }
    }

    // ---- epilogue: logits -> LDS (stride 65; reuses xs[0] region, 64*65 <= 64*68*2) ----
    float* lgt = &xs[0][0][0];
    #pragma unroll
    for (int i = 0; i < 4; ++i)
        #pragma unroll
        for (int j = 0; j < 4; ++j)
            lgt[(ty + 16 * i) * LSTR + (tx + 16 * j)] = acc[i][j];
    __syncthreads();

    // ---- per-token softmax + top-8 (one lane per token; fully unrolled: no scratch) ----
    if (tid < TM) {
        const int t = tid;
        float pv[NEXP];
        float mx = -INFINITY;
        #pragma unroll
        for (int e = 0; e < NEXP; ++e) {
            pv[e] = lgt[t * LSTR + e];
            mx = fmaxf(mx, pv[e]);
        }
        float s = 0.f;
        #pragma unroll
        for (int e = 0; e < NEXP; ++e) {
            pv[e] = expf(pv[e] - mx);
            s += pv[e];
        }
        #pragma unroll
        for (int e = 0; e < NEXP; ++e) {
            pv[e] = pv[e] / s;            // IEEE div to mirror softmax's unnormalized/sum
            lgt[t * LSTR + e] = pv[e];    // all_probs row (overwrite logits in place)
        }
        // top-8 by repeated masked max; strict '>' with ascending scan == lax.top_k
        // tie-break (lowest index first)
        unsigned long long selm = 0ull;
        float s8 = 0.f;
        float tpv[NSEL]; int tiv[NSEL];
        #pragma unroll
        for (int r = 0; r < NSEL; ++r) {
            float bm = -1.f; int bi = 0;
            #pragma unroll
            for (int e = 0; e < NEXP; ++e) {
                const bool ok = (((selm >> e) & 1ull) == 0ull) && (pv[e] > bm);
                if (ok) { bm = pv[e]; bi = e; }
            }
            selm |= (1ull << bi);
            tpv[r] = bm; tiv[r] = bi; s8 += bm;
        }
        const float den = s8 + 1e-9f;
        #pragma unroll
        for (int r = 0; r < NSEL; ++r) {
            tkp[t][r] = tpv[r] / den;
            tki[t][r] = tiv[r];
        }
    }
    __syncthreads();

    // ---- cooperative coalesced stores ----
    const int base_i = tokens * NSEL;        // indices section
    const int base_p = tokens * NSEL * 2;    // all_probs section
    for (int f = tid; f < TM * NSEL; f += 256) {
        const int t = f >> 3, r = f & 7;
        out[(tok0 + t) * NSEL + r]          = tkp[t][r];
        out[base_i + (tok0 + t) * NSEL + r] = (float)tki[t][r];
    }
    #pragma unroll
    for (int it = 0; it < 4; ++it) {
        const int f   = tid + 256 * it;      // float4 id over 64x64 probs
        const int row = f >> 4;
        const int c4  = f & 15;
        float4 v;
        v.x = lgt[row * LSTR + c4 * 4 + 0];
        v.y = lgt[row * LSTR + c4 * 4 + 1];
        v.z = lgt[row * LSTR + c4 * 4 + 2];
        v.w = lgt[row * LSTR + c4 * 4 + 3];
        *reinterpret_cast<float4*>(&out[base_p + (tok0 + row) * NEXP + c4 * 4]) = v;
    }
}

extern "C" void kernel_launch(void* const* d_in, const int* in_sizes, int n_in,
                              void* d_out, int out_size, void* d_ws, size_t ws_size,
                              hipStream_t stream)
{
    const float* x = (const float*)d_in[0];    // [B*S, D] = [16384, 2048]
    const float* w = (const float*)d_in[1];    // [E, D]   = [64, 2048]
    float* out = (float*)d_out;
    const int tokens = in_sizes[0] / DDIM;     // 16384
    const int grid = tokens / TM;              // 256 blocks -> 1 per CU
    router_kernel<<<grid, 256, 0, stream>>>(x, w, out, tokens);
}

// Round 3
// 458.840 us; speedup vs baseline: 1.0618x; 1.0618x over previous
//
#include <hip/hip_runtime.h>
#include <math.h>

#define DDIM 2048      // hidden dim
#define NEXP 64        // experts
#define NSEL 8         // top-k
#define TM   64        // tokens per block = wave width (lane -> token)
#define KC   64        // k-chunk floats per token
#define NCH  (DDIM/KC) // 32 chunks
#define EPW  8         // experts per lane (wave w owns experts [8w, 8w+8))
#define NT   512       // threads per block = 8 waves

// async global->LDS, 16B per lane
__device__ __forceinline__ void gload_lds16(const float* src, float* dst) {
    __builtin_amdgcn_global_load_lds(
        (const __attribute__((address_space(1))) void*)src,
        (__attribute__((address_space(3))) void*)dst, 16, 0, 0);
}

__global__ __launch_bounds__(NT, 2)
void router_kernel(const float* __restrict__ x,
                   const float* __restrict__ w,
                   float* __restrict__ out,
                   int tokens)
{
    __shared__ float xs[2][TM * KC];      // 2 x 16 KB, content quad-swizzled
    __shared__ float lgt[TM][NEXP + 1];   // logits/probs, stride 65 (conflict-free)

    const int tid   = threadIdx.x;
    const int lane  = tid & 63;
    const int wid   = __builtin_amdgcn_readfirstlane(tid >> 6);  // provably uniform
    const int ebase = wid * EPW;
    const int tok0  = blockIdx.x * TM;

    // ---- staging: thread f handles 16B quad f of the 16 KB chunk.
    // LDS dest linear (byte 16f = wave-uniform base + lane*16, required by HW);
    // global SOURCE pre-swizzled: physical quad q of row r holds logical quad q^(r&7).
    auto stage = [&](int buf, int c) {
        const int k0 = c * KC;
        #pragma unroll
        for (int it = 0; it < 2; ++it) {
            const int f  = tid + NT * it;          // 0..1023
            const int r  = f >> 4;                 // token row 0..63
            const int q  = f & 15;                 // physical quad
            const int lq = q ^ (r & 7);            // logical quad (swizzle)
            gload_lds16(&x[(size_t)(tok0 + r) * DDIM + k0 + 4 * lq],
                        &xs[buf][4 * f]);
        }
    };

    float acc[EPW] = {};
    const float* wbase = w + (size_t)ebase * DDIM;   // uniform per wave

    stage(0, 0);

    for (int c = 0; c < NCH; ++c) {
        __syncthreads();                  // drains vmcnt -> chunk c visible to all
        if (c + 1 < NCH) stage((c + 1) & 1, c + 1);

        const int b = c & 1;
        // per-chunk accumulator: 2-level summation (64-term in-order chunk sums,
        // then chunk-sum adds) — bit-identical fp sequence to the R1 kernel that
        // passed validation; keeps logits close to the numpy reference so the
        // top-8 boundary doesn't flip.
        float accc[EPW] = {};
        #pragma unroll
        for (int ks = 0; ks < 4; ++ks) {
            // lane reads its own token row: 4 x b128, swizzled -> 8 bank-sets hit evenly
            float xr[16];
            #pragma unroll
            for (int j = 0; j < 4; ++j) {
                const int Q = 4 * ks + j;                 // logical quad
                const int p = Q ^ (lane & 7);             // physical quad
                const float4 v = *reinterpret_cast<const float4*>(&xs[b][lane * KC + 4 * p]);
                xr[4 * j + 0] = v.x; xr[4 * j + 1] = v.y;
                xr[4 * j + 2] = v.z; xr[4 * j + 3] = v.w;
            }
            const int kk = c * KC + ks * 16;
            #pragma unroll
            for (int e = 0; e < EPW; ++e) {
                const float* wrow = &wbase[(size_t)e * DDIM + kk];  // uniform -> s_load
                #pragma unroll
                for (int k = 0; k < 16; ++k)
                    accc[e] = fmaf(wrow[k], xr[k], accc[e]);
            }
        }
        #pragma unroll
        for (int e = 0; e < EPW; ++e)
            acc[e] += accc[e];
    }

    // ---- logits -> LDS (stride 65: (65L + c) % 32 = (L+c) % 32, conflict-free)
    __syncthreads();
    #pragma unroll
    for (int e = 0; e < EPW; ++e)
        lgt[lane][ebase + e] = acc[e];
    __syncthreads();

    // ---- softmax + top-8: wave 0, one lane per token, all static indexing.
    // Numerics identical to the validated R1 epilogue: expf, IEEE divisions.
    if (tid < TM) {
        const int t = tid;
        float pv[NEXP];
        float mx = -INFINITY;
        #pragma unroll
        for (int e = 0; e < NEXP; ++e) { pv[e] = lgt[t][e]; mx = fmaxf(mx, pv[e]); }
        float s = 0.f;
        #pragma unroll
        for (int e = 0; e < NEXP; ++e) { pv[e] = expf(pv[e] - mx); s += pv[e]; }
        #pragma unroll
        for (int e = 0; e < NEXP; ++e) { pv[e] = pv[e] / s; lgt[t][e] = pv[e]; }

        // top-8 by repeated masked max; strict '>' ascending scan == lax.top_k tie-break
        unsigned long long selm = 0ull;
        float tpv[NSEL]; int tiv[NSEL]; float s8 = 0.f;
        #pragma unroll
        for (int r = 0; r < NSEL; ++r) {
            float bm = -1.f; int bi = 0;
            #pragma unroll
            for (int e = 0; e < NEXP; ++e) {
                const bool ok = (((selm >> e) & 1ull) == 0ull) && (pv[e] > bm);
                bm = ok ? pv[e] : bm;
                bi = ok ? e : bi;
            }
            selm |= (1ull << bi);
            tpv[r] = bm; tiv[r] = bi; s8 += bm;
        }
        const float den = s8 + 1e-9f;
        #pragma unroll
        for (int r = 0; r < NSEL; ++r) {
            out[(size_t)(tok0 + t) * NSEL + r] = tpv[r] / den;
            out[(size_t)tokens * NSEL + (size_t)(tok0 + t) * NSEL + r] = (float)tiv[r];
        }
    }
    __syncthreads();

    // ---- all_probs: cooperative coalesced float4 stores
    const size_t base_p = (size_t)tokens * NSEL * 2;
    #pragma unroll
    for (int it = 0; it < 2; ++it) {
        const int f = tid + NT * it;
        const int r = f >> 4, q = f & 15;
        float4 v;
        v.x = lgt[r][4 * q + 0]; v.y = lgt[r][4 * q + 1];
        v.z = lgt[r][4 * q + 2]; v.w = lgt[r][4 * q + 3];
        *reinterpret_cast<float4*>(&out[base_p + (size_t)(tok0 + r) * NEXP + 4 * q]) = v;
    }
}

extern "C" void kernel_launch(void* const* d_in, const int* in_sizes, int n_in,
                              void* d_out, int out_size, void* d_ws, size_t ws_size,
                              hipStream_t stream)
{
    const float* x = (const float*)d_in[0];    // [16384, 2048]
    const float* w = (const float*)d_in[1];    // [64, 2048]
    float* out = (float*)d_out;
    const int tokens = in_sizes[0] / DDIM;     // 16384
    router_kernel<<<tokens / TM, NT, 0, stream>>>(x, w, out, tokens);
}

// Round 4
// 273.689 us; speedup vs baseline: 1.7802x; 1.6765x over previous
//
#include <hip/hip_runtime.h>
#include <math.h>

#define DDIM 2048      // hidden dim
#define NEXP 64        // experts
#define NSEL 8         // top-k
#define TM   64        // tokens per block
#define KC   64        // k-chunk floats
#define NCH  (DDIM/KC) // 32 chunks
#define NT   256       // 4 waves: wave = 64 tok x 16 exp; lane = 8 tok x 2 exp

// async global->LDS, 16B per lane (dest must be wave-uniform base + lane*16)
__device__ __forceinline__ void gload_lds16(const float* src, float* dst) {
    __builtin_amdgcn_global_load_lds(
        (const __attribute__((address_space(1))) void*)src,
        (__attribute__((address_space(3))) void*)dst, 16, 0, 0);
}

__global__ __launch_bounds__(NT, 1)
void router_kernel(const float* __restrict__ x,
                   const float* __restrict__ w,
                   float* __restrict__ out,
                   int tokens)
{
    __shared__ __align__(16) float xs[2][TM * KC];    // 2 x 16 KB, quad-swizzled by token>>3
    __shared__ __align__(16) float ws[2][NEXP * KC];  // 2 x 16 KB, quad-swizzled by expert>>1
    __shared__ float lgt[TM][NEXP + 1];               // logits/probs, stride 65

    const int tid  = threadIdx.x;
    const int lane = tid & 63;
    const int wid  = tid >> 6;          // 0..3: wave owns experts [16*wid, 16*wid+16)
    const int tg   = lane >> 3;         // token group: tokens [8*tg, 8*tg+8)
    const int eg   = lane & 7;          // expert pair: experts 16*wid + 2*eg + {0,1}
    const int tok0 = blockIdx.x * TM;

    // ---- staging: LDS dest linear (HW requirement); global SOURCE pre-swizzled.
    // x row r: physical quad q holds logical quad q ^ ((r>>3)&7)
    // w row e: physical quad q holds logical quad q ^ ((e>>1)&7)
    auto stage = [&](int buf, int c) {
        const int k0 = c * KC;
        #pragma unroll
        for (int it = 0; it < 4; ++it) {
            const int gq = it * NT + tid;          // 0..1023
            const int r  = gq >> 4;
            const int q  = gq & 15;
            gload_lds16(&x[(size_t)(tok0 + r) * DDIM + k0 + 4 * (q ^ ((r >> 3) & 7))],
                        &xs[buf][4 * gq]);
        }
        #pragma unroll
        for (int it = 0; it < 4; ++it) {
            const int gq = it * NT + tid;
            const int r  = gq >> 4;
            const int q  = gq & 15;
            gload_lds16(&w[(size_t)r * DDIM + k0 + 4 * (q ^ ((r >> 1) & 7))],
                        &ws[buf][4 * gq]);
        }
    };

    float acc[8][2] = {};

    stage(0, 0);

    for (int c = 0; c < NCH; ++c) {
        __syncthreads();                    // chunk c resident in buf c&1
        if (c + 1 < NCH) stage((c + 1) & 1, c + 1);

        const int b = c & 1;
        // chunk-local accumulator: 64-term in-order sums, then one add per chunk —
        // bit-identical fp sequence to the validated R3 kernel.
        float accc[8][2] = {};
        #pragma unroll
        for (int kq = 0; kq < 16; ++kq) {
            float4 xv[8], wv[2];
            #pragma unroll
            for (int i = 0; i < 8; ++i)   // 8 broadcast groups on 8 disjoint bank-quads
                xv[i] = *reinterpret_cast<const float4*>(
                            &xs[b][(tg * 8 + i) * KC + 4 * (kq ^ tg)]);
            #pragma unroll
            for (int j = 0; j < 2; ++j) {
                const int er = wid * 16 + eg * 2 + j;
                wv[j] = *reinterpret_cast<const float4*>(
                            &ws[b][er * KC + 4 * (kq ^ eg)]);
            }
            #pragma unroll
            for (int i = 0; i < 8; ++i) {
                #pragma unroll
                for (int j = 0; j < 2; ++j) {
                    accc[i][j] = fmaf(xv[i].x, wv[j].x, accc[i][j]);
                    accc[i][j] = fmaf(xv[i].y, wv[j].y, accc[i][j]);
                    accc[i][j] = fmaf(xv[i].z, wv[j].z, accc[i][j]);
                    accc[i][j] = fmaf(xv[i].w, wv[j].w, accc[i][j]);
                }
            }
        }
        #pragma unroll
        for (int i = 0; i < 8; ++i)
            #pragma unroll
            for (int j = 0; j < 2; ++j)
                acc[i][j] += accc[i][j];
    }

    // ---- logits -> LDS (stride 65; 2 lanes/bank worst case = free)
    __syncthreads();
    #pragma unroll
    for (int i = 0; i < 8; ++i)
        #pragma unroll
        for (int j = 0; j < 2; ++j)
            lgt[tg * 8 + i][wid * 16 + eg * 2 + j] = acc[i][j];
    __syncthreads();

    // ---- softmax + top-8: wave 0, one lane per token (validated R3 epilogue,
    // numerics identical: expf, IEEE divisions, strict-'>' ascending scan)
    if (tid < TM) {
        const int t = tid;
        float pv[NEXP];
        float mx = -INFINITY;
        #pragma unroll
        for (int e = 0; e < NEXP; ++e) { pv[e] = lgt[t][e]; mx = fmaxf(mx, pv[e]); }
        float s = 0.f;
        #pragma unroll
        for (int e = 0; e < NEXP; ++e) { pv[e] = expf(pv[e] - mx); s += pv[e]; }
        #pragma unroll
        for (int e = 0; e < NEXP; ++e) { pv[e] = pv[e] / s; lgt[t][e] = pv[e]; }

        unsigned long long selm = 0ull;
        float tpv[NSEL]; int tiv[NSEL]; float s8 = 0.f;
        #pragma unroll
        for (int r = 0; r < NSEL; ++r) {
            float bm = -1.f; int bi = 0;
            #pragma unroll
            for (int e = 0; e < NEXP; ++e) {
                const bool ok = (((selm >> e) & 1ull) == 0ull) && (pv[e] > bm);
                bm = ok ? pv[e] : bm;
                bi = ok ? e : bi;
            }
            selm |= (1ull << bi);
            tpv[r] = bm; tiv[r] = bi; s8 += bm;
        }
        const float den = s8 + 1e-9f;
        #pragma unroll
        for (int r = 0; r < NSEL; ++r) {
            out[(size_t)(tok0 + t) * NSEL + r] = tpv[r] / den;
            out[(size_t)tokens * NSEL + (size_t)(tok0 + t) * NSEL + r] = (float)tiv[r];
        }
    }
    __syncthreads();

    // ---- all_probs: cooperative coalesced float4 stores
    const size_t base_p = (size_t)tokens * NSEL * 2;
    #pragma unroll
    for (int it = 0; it < 4; ++it) {
        const int f = it * NT + tid;         // 0..1023 float4s over 64x64
        const int r = f >> 4, q = f & 15;
        float4 v;
        v.x = lgt[r][4 * q + 0]; v.y = lgt[r][4 * q + 1];
        v.z = lgt[r][4 * q + 2]; v.w = lgt[r][4 * q + 3];
        *reinterpret_cast<float4*>(&out[base_p + (size_t)(tok0 + r) * NEXP + 4 * q]) = v;
    }
}

extern "C" void kernel_launch(void* const* d_in, const int* in_sizes, int n_in,
                              void* d_out, int out_size, void* d_ws, size_t ws_size,
                              hipStream_t stream)
{
    const float* x = (const float*)d_in[0];    // [16384, 2048]
    const float* w = (const float*)d_in[1];    // [64, 2048]
    float* out = (float*)d_out;
    const int tokens = in_sizes[0] / DDIM;     // 16384
    router_kernel<<<tokens / TM, NT, 0, stream>>>(x, w, out, tokens);
}

// Round 5
// 269.366 us; speedup vs baseline: 1.8088x; 1.0160x over previous
//
#include <hip/hip_runtime.h>
#include <math.h>

#define DDIM 2048      // hidden dim
#define NEXP 64        // experts
#define NSEL 8         // top-k
#define TM   64        // tokens per block
#define KC   64        // k-chunk floats
#define NCH  (DDIM/KC) // 32 chunks
#define NT   256       // 4 waves; lane tile = 4 tok x 4 exp (T=E=4 minimizes LDS traffic)

// async global->LDS, 16B per lane (dest must be wave-uniform base + lane*16)
__device__ __forceinline__ void gload_lds16(const float* src, float* dst) {
    __builtin_amdgcn_global_load_lds(
        (const __attribute__((address_space(1))) void*)src,
        (__attribute__((address_space(3))) void*)dst, 16, 0, 0);
}

__global__ __launch_bounds__(NT, 1)
void router_kernel(const float* __restrict__ x,
                   const float* __restrict__ w,
                   float* __restrict__ out,
                   int tokens)
{
    __shared__ __align__(16) float xs[2][TM * KC];    // 2 x 16 KB, quad-swizzled by row>>2
    __shared__ __align__(16) float ws[2][NEXP * KC];  // 2 x 16 KB, quad-swizzled by row>>2
    __shared__ float lgt[TM][NEXP + 1];               // logits/probs, stride 65

    const int tid  = threadIdx.x;
    const int tgi  = tid >> 4;          // token group 0..15: tokens [4*tgi, 4*tgi+4)
    const int egi  = tid & 15;          // expert group 0..15: experts [4*egi, 4*egi+4)
    const int tok0 = blockIdx.x * TM;

    // ---- staging: LDS dest linear (HW requirement); global SOURCE pre-swizzled.
    // row r, physical quad q holds logical quad q ^ ((r>>2)&7)  (involution)
    auto stage = [&](int buf, int c) {
        const int k0 = c * KC;
        #pragma unroll
        for (int it = 0; it < 4; ++it) {
            const int gq = it * NT + tid;          // 0..1023
            const int r  = gq >> 4;
            const int q  = gq & 15;
            gload_lds16(&x[(size_t)(tok0 + r) * DDIM + k0 + 4 * (q ^ ((r >> 2) & 7))],
                        &xs[buf][4 * gq]);
        }
        #pragma unroll
        for (int it = 0; it < 4; ++it) {
            const int gq = it * NT + tid;
            const int r  = gq >> 4;
            const int q  = gq & 15;
            gload_lds16(&w[(size_t)r * DDIM + k0 + 4 * (q ^ ((r >> 2) & 7))],
                        &ws[buf][4 * gq]);
        }
    };

    // per-kq loads: x rows 4*tgi+i (XOR tgi&7 -> 4 distinct bank-quads, 16-lane
    // broadcast, conflict-free); w rows 4*egi+j (XOR egi&7 -> 2-way worst = free)
    #define LOADQ(XV, WV, B, KQ)                                                   \
        {                                                                          \
            _Pragma("unroll")                                                      \
            for (int i = 0; i < 4; ++i)                                            \
                XV[i] = *reinterpret_cast<const float4*>(                          \
                    &xs[B][(4 * tgi + i) * KC + 4 * ((KQ) ^ (tgi & 7))]);          \
            _Pragma("unroll")                                                      \
            for (int j = 0; j < 4; ++j)                                            \
                WV[j] = *reinterpret_cast<const float4*>(                          \
                    &ws[B][(4 * egi + j) * KC + 4 * ((KQ) ^ (egi & 7))]);          \
        }

    #define FMAQ(XV, WV)                                                           \
        {                                                                          \
            _Pragma("unroll")                                                      \
            for (int i = 0; i < 4; ++i) {                                          \
                _Pragma("unroll")                                                  \
                for (int j = 0; j < 4; ++j) {                                      \
                    accc[i][j] = fmaf(XV[i].x, WV[j].x, accc[i][j]);               \
                    accc[i][j] = fmaf(XV[i].y, WV[j].y, accc[i][j]);               \
                    accc[i][j] = fmaf(XV[i].z, WV[j].z, accc[i][j]);               \
                    accc[i][j] = fmaf(XV[i].w, WV[j].w, accc[i][j]);               \
                }                                                                  \
            }                                                                      \
        }

    float acc[4][4] = {};

    stage(0, 0);

    for (int c = 0; c < NCH; ++c) {
        __syncthreads();                    // chunk c resident in buf c&1
        if (c + 1 < NCH) stage((c + 1) & 1, c + 1);

        const int b = c & 1;
        // chunk-local accumulator: 64-term in-order sums per output, then one add
        // per chunk — bit-identical fp sequence to the validated R4 kernel.
        float accc[4][4] = {};
        float4 xA[4], wA[4], xB[4], wB[4];
        // depth-1 software pipeline: load kq+1 while computing kq
        LOADQ(xA, wA, b, 0)
        #pragma unroll
        for (int kq = 0; kq < 16; kq += 2) {
            LOADQ(xB, wB, b, kq + 1)
            FMAQ(xA, wA)
            if (kq + 2 < 16) LOADQ(xA, wA, b, kq + 2)
            FMAQ(xB, wB)
        }
        #pragma unroll
        for (int i = 0; i < 4; ++i)
            #pragma unroll
            for (int j = 0; j < 4; ++j)
                acc[i][j] += accc[i][j];
    }

    // ---- logits -> LDS (stride 65)
    __syncthreads();
    #pragma unroll
    for (int i = 0; i < 4; ++i)
        #pragma unroll
        for (int j = 0; j < 4; ++j)
            lgt[4 * tgi + i][4 * egi + j] = acc[i][j];
    __syncthreads();

    // ---- softmax + top-8: wave 0, one lane per token (validated epilogue,
    // numerics identical: expf, IEEE divisions, strict-'>' ascending scan)
    if (tid < TM) {
        const int t = tid;
        float pv[NEXP];
        float mx = -INFINITY;
        #pragma unroll
        for (int e = 0; e < NEXP; ++e) { pv[e] = lgt[t][e]; mx = fmaxf(mx, pv[e]); }
        float s = 0.f;
        #pragma unroll
        for (int e = 0; e < NEXP; ++e) { pv[e] = expf(pv[e] - mx); s += pv[e]; }
        #pragma unroll
        for (int e = 0; e < NEXP; ++e) { pv[e] = pv[e] / s; lgt[t][e] = pv[e]; }

        unsigned long long selm = 0ull;
        float tpv[NSEL]; int tiv[NSEL]; float s8 = 0.f;
        #pragma unroll
        for (int r = 0; r < NSEL; ++r) {
            float bm = -1.f; int bi = 0;
            #pragma unroll
            for (int e = 0; e < NEXP; ++e) {
                const bool ok = (((selm >> e) & 1ull) == 0ull) && (pv[e] > bm);
                bm = ok ? pv[e] : bm;
                bi = ok ? e : bi;
            }
            selm |= (1ull << bi);
            tpv[r] = bm; tiv[r] = bi; s8 += bm;
        }
        const float den = s8 + 1e-9f;
        #pragma unroll
        for (int r = 0; r < NSEL; ++r) {
            out[(size_t)(tok0 + t) * NSEL + r] = tpv[r] / den;
            out[(size_t)tokens * NSEL + (size_t)(tok0 + t) * NSEL + r] = (float)tiv[r];
        }
    }
    __syncthreads();

    // ---- all_probs: cooperative coalesced float4 stores
    const size_t base_p = (size_t)tokens * NSEL * 2;
    #pragma unroll
    for (int it = 0; it < 4; ++it) {
        const int f = it * NT + tid;         // 0..1023 float4s over 64x64
        const int r = f >> 4, q = f & 15;
        float4 v;
        v.x = lgt[r][4 * q + 0]; v.y = lgt[r][4 * q + 1];
        v.z = lgt[r][4 * q + 2]; v.w = lgt[r][4 * q + 3];
        *reinterpret_cast<float4*>(&out[base_p + (size_t)(tok0 + r) * NEXP + 4 * q]) = v;
    }
}

extern "C" void kernel_launch(void* const* d_in, const int* in_sizes, int n_in,
                              void* d_out, int out_size, void* d_ws, size_t ws_size,
                              hipStream_t stream)
{
    const float* x = (const float*)d_in[0];    // [16384, 2048]
    const float* w = (const float*)d_in[1];    // [64, 2048]
    float* out = (float*)d_out;
    const int tokens = in_sizes[0] / DDIM;     // 16384
    router_kernel<<<tokens / TM, NT, 0, stream>>>(x, w, out, tokens);
}